// Round 1
// 667.548 us; speedup vs baseline: 1.1934x; 1.1934x over previous
//
#include <hip/hip_runtime.h>
#include <cstdint>
#include <cstddef>

#define NVOX 300000
#define SB 4194304      // T*H*W = 2^22
#define ST 262144       // H*W   = 2^18
#define SHH 512         // W     = 2^9
#define SENT 33554432   // 2^25
#define NWORDS (SENT/64) // 524288 = 2^19

typedef __attribute__((ext_vector_type(8))) short short8;
typedef __attribute__((ext_vector_type(4))) float f32x4;

static __device__ __forceinline__ float bf2f(unsigned short u){
  return __uint_as_float(((unsigned)u) << 16);
}
static __device__ __forceinline__ unsigned short f2bf(float f){
  unsigned u = __float_as_uint(f);
  u = u + 0x7fffu + ((u >> 16) & 1u);
  return (unsigned short)(u >> 16);
}
static __device__ __forceinline__ short8 pack8(float4 a, float4 b){
  short8 s;
  s[0]=(short)f2bf(a.x); s[1]=(short)f2bf(a.y); s[2]=(short)f2bf(a.z); s[3]=(short)f2bf(a.w);
  s[4]=(short)f2bf(b.x); s[5]=(short)f2bf(b.y); s[6]=(short)f2bf(b.z); s[7]=(short)f2bf(b.w);
  return s;
}

// rank of a set bit = number of set bits before it (global, via scan structures)
static __device__ __forceinline__ unsigned rank_of(int l,
    const unsigned long long* __restrict__ bits,
    const unsigned* __restrict__ coarse,
    const unsigned* __restrict__ blockExcl){
  int w = l >> 6;
  unsigned long long m = 1ull << (l & 63);
  return coarse[w] + blockExcl[w >> 12]
       + (unsigned)__popcll(bits[w] & (m - 1ull));
}

// ---- pack W (fp32 KxN) -> fragment-contiguous bf16 layout ----
__global__ void pack_w(const float* __restrict__ W, unsigned short* __restrict__ Wt){
  int i = blockIdx.x*256 + threadIdx.x;  // 16384 elements
  int j = i & 7, lane = (i >> 3) & 63, ks = (i >> 9) & 3, nt = i >> 11;
  int k = ks*32 + (lane >> 4)*8 + j;
  int n = nt*16 + (lane & 15);
  Wt[i] = f2bf(W[k*128 + n]);
}

// ---------------- mark: compute lin, set presence bit, detect duplicates ----
__global__ void mark_kernel(const int* __restrict__ idx,
                            unsigned long long* __restrict__ bits,
                            unsigned long long* __restrict__ dupbits,
                            int* __restrict__ lin,
                            int* __restrict__ duplist,
                            int* __restrict__ dupcount){
  int i = blockIdx.x*256 + threadIdx.x;
  if(i >= NVOX) return;
  int4 v = ((const int4*)idx)[i];
  int l = v.x*SB + v.y*ST + v.z*SHH + v.w;
  lin[i] = l;
  unsigned long long m = 1ull << (l & 63);
  unsigned long long old = atomicOr(&bits[l >> 6], m);
  if(old & m){
    // secondary contributor to a duplicated lin: record it
    atomicOr(&dupbits[l >> 6], m);
    int s = atomicAdd(dupcount, 1);
    duplist[s] = i;
  }
}

// ---------------- scan of per-word popcounts ----------------
__global__ void scan1_kernel(const unsigned long long* __restrict__ bits,
                             unsigned* __restrict__ coarse,
                             unsigned* __restrict__ blockSums){
  __shared__ unsigned sh[256];
  int t = threadIdx.x, blk = blockIdx.x;
  int w0 = blk*4096 + t*16;
  unsigned p[16]; unsigned s = 0;
  #pragma unroll
  for(int k=0;k<16;k++){ unsigned c = (unsigned)__popcll(bits[w0+k]); p[k] = s; s += c; }
  sh[t] = s; __syncthreads();
  for(int off=1; off<256; off<<=1){
    unsigned v = (t >= off) ? sh[t-off] : 0u;
    __syncthreads();
    sh[t] += v;
    __syncthreads();
  }
  unsigned texcl = (t == 0) ? 0u : sh[t-1];
  #pragma unroll
  for(int k=0;k<16;k++) coarse[w0+k] = texcl + p[k];
  if(t == 255) blockSums[blk] = sh[255];
}

__global__ void scan2_kernel(const unsigned* __restrict__ blockSums,
                             unsigned* __restrict__ blockExcl){
  __shared__ unsigned sh[128];
  int t = threadIdx.x; // 128 threads
  sh[t] = blockSums[t]; __syncthreads();
  for(int off=1; off<128; off<<=1){
    unsigned v = (t >= off) ? sh[t-off] : 0u;
    __syncthreads();
    sh[t] += v;
    __syncthreads();
  }
  if(t == 0) blockExcl[0] = 0u;
  blockExcl[t+1] = sh[t];
}

// ---------------- emit comb_idx for real unique rows ----------------
__global__ void emit_kernel(const unsigned long long* __restrict__ bits,
                            const unsigned* __restrict__ coarse,
                            const unsigned* __restrict__ blockExcl,
                            float* __restrict__ out_comb){
  int w = blockIdx.x*256 + threadIdx.x;
  if(w >= NWORDS) return;
  unsigned long long bw = bits[w];
  if(!bw) return;
  unsigned j = coarse[w] + blockExcl[w >> 12];
  while(bw){
    int p = __builtin_ctzll(bw);
    bw &= bw - 1;
    int v = (w << 6) | p;
    int cb = v >> 22;
    int r  = v & (SB - 1);
    int ct = r >> 18;
    r &= (ST - 1);
    int ch = r >> 9;
    int cw = r & 511;
    ((float4*)out_comb)[j] = make_float4((float)cb,(float)ct,(float)ch,(float)cw);
    j++;
  }
}

// ---------------- zero accum rows of duplicated lins (pre-scatter) ---------
__global__ void zerodup_kernel(const int* __restrict__ duplist,
    const int* __restrict__ dupcount, const int* __restrict__ lin,
    const unsigned long long* __restrict__ bits,
    const unsigned* __restrict__ coarse, const unsigned* __restrict__ blockExcl,
    float* __restrict__ out_merged)
{
  int cnt = *dupcount;
  int lane = threadIdx.x & 63;
  for(int e = blockIdx.x*4 + (threadIdx.x >> 6); e < cnt; e += gridDim.x*4){
    int l = lin[duplist[e]];
    unsigned j = rank_of(l, bits, coarse, blockExcl);
    *(float2*)(out_merged + (size_t)j*128 + 2*lane) = make_float2(0.f, 0.f);
  }
}

// ---- fused MLP: X @ W1 -> LN -> ReLU -> @ W2 -> LN, MFMA bf16 -------------
// block = 256 thr = 4 waves; 64 rows/block, each wave owns 16 rows x 128 cols.
// v2: A-frags loaded DIRECTLY from global (no input staging / no barrier) --
// the LDS stage was a pure layout transform with zero inter-wave reuse.
// xs LDS is used only for the GEMM1->GEMM2 relayout (wave-private rows, no
// barrier needed: per-wave DS ops complete in order) and output staging.
__global__ __launch_bounds__(256) void fused_mlp(
    const float* __restrict__ X,
    const unsigned short* __restrict__ w1t, const float* __restrict__ g1v,
    const float* __restrict__ b1v,
    const unsigned short* __restrict__ w2t, const float* __restrict__ g2v,
    const float* __restrict__ b2v,
    unsigned short* __restrict__ Y, float* __restrict__ sq, int nrows)
{
  __shared__ __align__(16) unsigned short xs[64][136];  // stride 272B
  __shared__ float sqs[4][128];                         // per-wave SE partials
  const int t = threadIdx.x;
  const int rowbase = blockIdx.x * 64;
  const int wave = t >> 6, quad = (t >> 4) & 3, l15 = t & 15;
  const int wbase = wave * 16;
  const int lane8 = (t & 63) * 8;   // short offset of this lane's B-frag
  const int lrow = wbase + l15;     // local row (xs index)
  const int grow = rowbase + lrow;  // global row
  const int kofs = quad * 8;
  const bool rv_a = grow < nrows;

  // ---- direct A-frag loads: per lane two contiguous float4 per frag ----
  short8 a0, a1, a2, a3;
  {
    const float* xp = X + (size_t)grow * 128 + kofs;
    float4 z = make_float4(0.f,0.f,0.f,0.f);
    float4 u0=z,u1=z,u2=z,u3=z,u4=z,u5=z,u6=z,u7=z;
    if (rv_a) {
      u0 = ((const float4*)(xp      ))[0];
      u1 = ((const float4*)(xp +   4))[0];
      u2 = ((const float4*)(xp +  32))[0];
      u3 = ((const float4*)(xp +  36))[0];
      u4 = ((const float4*)(xp +  64))[0];
      u5 = ((const float4*)(xp +  68))[0];
      u6 = ((const float4*)(xp +  96))[0];
      u7 = ((const float4*)(xp + 100))[0];
    }
    a0 = pack8(u0, u1); a1 = pack8(u2, u3);
    a2 = pack8(u4, u5); a3 = pack8(u6, u7);
  }

  // ================= GEMM1 + LN1 + ReLU =================
  {
    f32x4 acc[8];
    #pragma unroll
    for (int nt = 0; nt < 8; nt++) {
      const unsigned short* wp = w1t + nt*2048 + lane8;
      short8 bv0 = *(const short8*)(wp);
      short8 bv1 = *(const short8*)(wp + 512);
      short8 bv2 = *(const short8*)(wp + 1024);
      short8 bv3 = *(const short8*)(wp + 1536);
      f32x4 c = {0.f,0.f,0.f,0.f};
      c = __builtin_amdgcn_mfma_f32_16x16x32_bf16(a0, bv0, c, 0, 0, 0);
      c = __builtin_amdgcn_mfma_f32_16x16x32_bf16(a1, bv1, c, 0, 0, 0);
      c = __builtin_amdgcn_mfma_f32_16x16x32_bf16(a2, bv2, c, 0, 0, 0);
      c = __builtin_amdgcn_mfma_f32_16x16x32_bf16(a3, bv3, c, 0, 0, 0);
      acc[nt] = c;
    }

    float gg[8], bb[8];
    #pragma unroll
    for (int nt = 0; nt < 8; nt++) {
      gg[nt] = g1v[nt*16 + l15]; bb[nt] = b1v[nt*16 + l15];
    }
    #pragma unroll
    for (int r = 0; r < 4; r++) {
      float s = 0.f, q = 0.f;
      #pragma unroll
      for (int nt = 0; nt < 8; nt++) { float v = acc[nt][r]; s += v; q += v*v; }
      #pragma unroll
      for (int mm = 1; mm < 16; mm <<= 1) { s += __shfl_xor(s, mm); q += __shfl_xor(q, mm); }
      float mu = s * (1.f/128.f);
      float var = fmaxf(q * (1.f/128.f) - mu*mu, 0.f);
      float rinv = rsqrtf(var + 1e-5f);
      int orow = wbase + quad*4 + r;
      #pragma unroll
      for (int nt = 0; nt < 8; nt++) {
        float v = (acc[nt][r] - mu) * rinv * gg[nt] + bb[nt];
        v = fmaxf(v, 0.f);
        xs[orow][nt*16 + l15] = f2bf(v);   // wave-private rows: no barrier
      }
    }
  }

  // ================= GEMM2 + LN2 + SE partial sums =================
  {
    short8 c0 = *(const short8*)&xs[lrow][  0 + kofs];
    short8 c1 = *(const short8*)&xs[lrow][ 32 + kofs];
    short8 c2 = *(const short8*)&xs[lrow][ 64 + kofs];
    short8 c3 = *(const short8*)&xs[lrow][ 96 + kofs];

    f32x4 acc[8];
    #pragma unroll
    for (int nt = 0; nt < 8; nt++) {
      const unsigned short* wp = w2t + nt*2048 + lane8;
      short8 bv0 = *(const short8*)(wp);
      short8 bv1 = *(const short8*)(wp + 512);
      short8 bv2 = *(const short8*)(wp + 1024);
      short8 bv3 = *(const short8*)(wp + 1536);
      f32x4 c = {0.f,0.f,0.f,0.f};
      c = __builtin_amdgcn_mfma_f32_16x16x32_bf16(c0, bv0, c, 0, 0, 0);
      c = __builtin_amdgcn_mfma_f32_16x16x32_bf16(c1, bv1, c, 0, 0, 0);
      c = __builtin_amdgcn_mfma_f32_16x16x32_bf16(c2, bv2, c, 0, 0, 0);
      c = __builtin_amdgcn_mfma_f32_16x16x32_bf16(c3, bv3, c, 0, 0, 0);
      acc[nt] = c;
    }

    float gg[8], bb[8], ch[8];
    #pragma unroll
    for (int nt = 0; nt < 8; nt++) {
      gg[nt] = g2v[nt*16 + l15]; bb[nt] = b2v[nt*16 + l15]; ch[nt] = 0.f;
    }
    #pragma unroll
    for (int r = 0; r < 4; r++) {
      float s = 0.f, q = 0.f;
      #pragma unroll
      for (int nt = 0; nt < 8; nt++) { float v = acc[nt][r]; s += v; q += v*v; }
      #pragma unroll
      for (int mm = 1; mm < 16; mm <<= 1) { s += __shfl_xor(s, mm); q += __shfl_xor(q, mm); }
      float mu = s * (1.f/128.f);
      float var = fmaxf(q * (1.f/128.f) - mu*mu, 0.f);
      float rinv = rsqrtf(var + 1e-5f);
      int orow = wbase + quad*4 + r;
      bool rv = (rowbase + orow) < nrows;
      #pragma unroll
      for (int nt = 0; nt < 8; nt++) {
        float v = (acc[nt][r] - mu) * rinv * gg[nt] + bb[nt];
        if (rv) ch[nt] += v;
        xs[orow][nt*16 + l15] = f2bf(v);
      }
    }
    // SE channel partials: reduce across quads, plain store to per-wave bank
    #pragma unroll
    for (int nt = 0; nt < 8; nt++) {
      float v = ch[nt];
      v += __shfl_xor(v, 16); v += __shfl_xor(v, 32);
      if (quad == 0) sqs[wave][nt*16 + l15] = v;
    }
  }

  __syncthreads();
  // vector store y2: bf16, fully coalesced ushort8
  #pragma unroll
  for (int mm = 0; mm < 4; mm++) {
    int c = mm*256 + t;             // 1024 chunks of 8 shorts
    int row = c >> 4, s8 = c & 15;
    if (rowbase + row < nrows) {
      short8 v = *(const short8*)&xs[row][s8*8];
      *(short8*)(Y + (size_t)(rowbase+row)*128 + s8*8) = v;
    }
  }
  if (t < 128) atomicAdd(&sq[t], sqs[0][t] + sqs[1][t] + sqs[2][t] + sqs[3][t]);
}

// ---------------- SE: mean -> fc -> relu -> fc -> sigmoid ----------------
__global__ void se_kernel(const float* __restrict__ sq, const float* __restrict__ w1,
    const float* __restrict__ b1, const float* __restrict__ w2,
    const float* __restrict__ b2, float* __restrict__ scale)
{
  __shared__ float mean[128];
  __shared__ float h1[32];
  int t = threadIdx.x; // 128 threads
  mean[t] = sq[t] * (1.f/(float)NVOX);
  __syncthreads();
  if(t < 32){
    float s = b1[t];
    for(int c=0;c<128;c++) s += mean[c]*w1[c*32+t];
    h1[t] = fmaxf(s, 0.f);
  }
  __syncthreads();
  float s = b2[t];
  for(int j=0;j<32;j++) s += h1[j]*w2[j*128+t];
  scale[t] = 1.f/(1.f + expf(-s));
}

// ---- scatter v2: unique rows -> fused relu/valid + PLAIN stores (no atomics,
// no finalize pass); duplicated rows (~1e-3 of rows) -> atomicAdd raw sums ----
__global__ void scatter_kernel(const unsigned short* __restrict__ y2,
    const float* __restrict__ feats, const float* __restrict__ scale,
    const int* __restrict__ lin, const unsigned long long* __restrict__ bits,
    const unsigned long long* __restrict__ dupbits,
    const unsigned* __restrict__ coarse, const unsigned* __restrict__ blockExcl,
    float* __restrict__ out_merged, float* __restrict__ out_valid)
{
  int row = blockIdx.x*4 + (threadIdx.x >> 6);
  int lane = threadIdx.x & 63;
  int l = lin[row];
  int w = l >> 6;
  unsigned long long m = 1ull << (l & 63);
  unsigned j = coarse[w] + blockExcl[w >> 12]
             + (unsigned)__popcll(bits[w] & (m - 1ull));
  size_t rb = (size_t)row * 128;
  unsigned yy = *(const unsigned*)(y2 + rb + 2*lane);
  float2 ff = *(const float2*)(feats + rb + 2*lane);
  float2 ss = *(const float2*)(scale + 2*lane);
  float v0 = bf2f((unsigned short)(yy & 0xffffu)) * ss.x + ff.x;
  float v1 = bf2f((unsigned short)(yy >> 16))     * ss.y + ff.y;
  size_t ob = (size_t)j * 128;
  if (dupbits[w] & m) {           // wave-uniform branch (per-row condition)
    atomicAdd(out_merged + ob + 2*lane,     v0);
    atomicAdd(out_merged + ob + 2*lane + 1, v1);
  } else {
    float s = fabsf(v0) + fabsf(v1);
    #pragma unroll
    for(int mm=1; mm<64; mm<<=1) s += __shfl_xor(s, mm);
    bool valid = s > 1e-8f;
    float2 o;
    o.x = valid ? fmaxf(v0, 0.f) : 0.f;
    o.y = valid ? fmaxf(v1, 0.f) : 0.f;
    *(float2*)(out_merged + ob + 2*lane) = o;
    if (lane == 0) out_valid[j] = valid ? 1.f : 0.f;
  }
}

// ---------------- finalize only the duplicated rows (claim via dupbits) ----
__global__ void dupfinal_kernel(const int* __restrict__ duplist,
    const int* __restrict__ dupcount, const int* __restrict__ lin,
    unsigned long long* __restrict__ dupbits,
    const unsigned long long* __restrict__ bits,
    const unsigned* __restrict__ coarse, const unsigned* __restrict__ blockExcl,
    float* __restrict__ out_merged, float* __restrict__ out_valid)
{
  int cnt = *dupcount;
  int lane = threadIdx.x & 63;
  for(int e = blockIdx.x*4 + (threadIdx.x >> 6); e < cnt; e += gridDim.x*4){
    int l = lin[duplist[e]];
    int w = l >> 6;
    unsigned long long m = 1ull << (l & 63);
    int claimed = 0;
    if (lane == 0){
      unsigned long long old = atomicAnd(&dupbits[w], ~m);
      claimed = (old & m) ? 1 : 0;
    }
    claimed = __shfl(claimed, 0);
    if (!claimed) continue;       // another entry with the same lin owns it
    unsigned j = coarse[w] + blockExcl[w >> 12]
               + (unsigned)__popcll(bits[w] & (m - 1ull));
    size_t ob = (size_t)j * 128;
    float2 v = *(float2*)(out_merged + ob + 2*lane);
    float s = fabsf(v.x) + fabsf(v.y);
    #pragma unroll
    for(int mm=1; mm<64; mm<<=1) s += __shfl_xor(s, mm);
    bool valid = s > 1e-8f;
    float2 o;
    o.x = valid ? fmaxf(v.x, 0.f) : 0.f;
    o.y = valid ? fmaxf(v.y, 0.f) : 0.f;
    *(float2*)(out_merged + ob + 2*lane) = o;
    if (lane == 0) out_valid[j] = valid ? 1.f : 0.f;
  }
}

// ---------------- pad rows [U, 2N): zeros + sentinel comb + valid=0 --------
// blocks [0,512): grid-stride over [U, NVOX) (tiny: N - U == #dups)
// blocks [512, 512+NVOX/4): unconditional rows [NVOX, 2*NVOX)
__global__ void padfill_kernel(const unsigned* __restrict__ blockExcl,
    float* __restrict__ out_merged, float* __restrict__ out_comb,
    float* __restrict__ out_valid)
{
  int lane = threadIdx.x & 63;
  int wv = threadIdx.x >> 6;
  if (blockIdx.x < 512) {
    unsigned U = blockExcl[128];
    for (unsigned r = U + blockIdx.x*4 + wv; r < NVOX; r += 512*4) {
      *(float2*)(out_merged + (size_t)r*128 + 2*lane) = make_float2(0.f, 0.f);
      if (lane == 0) {
        out_valid[r] = 0.f;
        ((float4*)out_comb)[r] = make_float4(8.f, 0.f, 0.f, 0.f);
      }
    }
  } else {
    int r = NVOX + (blockIdx.x - 512)*4 + wv;
    *(float2*)(out_merged + (size_t)r*128 + 2*lane) = make_float2(0.f, 0.f);
    if (lane == 0) {
      out_valid[r] = 0.f;
      ((float4*)out_comb)[r] = make_float4(8.f, 0.f, 0.f, 0.f);
    }
  }
}

extern "C" void kernel_launch(void* const* d_in, const int* in_sizes, int n_in,
                              void* d_out, int out_size, void* d_ws, size_t ws_size,
                              hipStream_t stream)
{
  const float* feats   = (const float*)d_in[0];
  const int*   indices = (const int*)d_in[1];
  const float* W1  = (const float*)d_in[2];
  const float* g1  = (const float*)d_in[3];
  const float* b1  = (const float*)d_in[4];
  const float* W2  = (const float*)d_in[5];
  const float* g2  = (const float*)d_in[6];
  const float* b2  = (const float*)d_in[7];
  const float* sw1 = (const float*)d_in[8];
  const float* sb1 = (const float*)d_in[9];
  const float* sw2 = (const float*)d_in[10];
  const float* sb2 = (const float*)d_in[11];

  float* out_merged = (float*)d_out;                        // [2N,128]
  float* out_comb   = out_merged + (size_t)2*NVOX*128;      // [2N,4]
  float* out_valid  = out_comb   + (size_t)2*NVOX*4;        // [2N]

  char* cur = (char*)d_ws;
  auto alloc = [&](size_t b) -> void* {
    void* p = (void*)cur;
    cur += (b + 255) & ~(size_t)255;
    return p;
  };
  unsigned short*      y2        = (unsigned short*)alloc((size_t)NVOX*128*2);
  unsigned long long*  bits      = (unsigned long long*)alloc((size_t)NWORDS*8);
  unsigned long long*  dupbits   = (unsigned long long*)alloc((size_t)NWORDS*8); // contiguous w/ bits
  unsigned*            coarse    = (unsigned*)alloc((size_t)NWORDS*4);
  unsigned*            blockSums = (unsigned*)alloc(128*4);
  unsigned*            blockExcl = (unsigned*)alloc(129*4);
  float*               sq        = (float*)alloc(128*4);
  int*                 dupcount  = (int*)alloc(4);          // contiguous w/ sq
  float*               scale     = (float*)alloc(128*4);
  int*                 lin       = (int*)alloc((size_t)NVOX*4);
  int*                 duplist   = (int*)alloc((size_t)NVOX*4);
  unsigned short*      w1t       = (unsigned short*)alloc(128*128*2);
  unsigned short*      w2t       = (unsigned short*)alloc(128*128*2);

  // bits + dupbits are adjacent 256-aligned 4MB blocks -> one 8MB clear
  hipMemsetAsync(bits, 0, (size_t)NWORDS*8*2, stream);
  // sq (512B) + dupcount (256B slot) adjacent -> one clear
  hipMemsetAsync(sq, 0, 512 + 256, stream);
  // NOTE: no out_merged memset anymore — scatter stores final values directly;
  // padfill covers rows [U,2N); zerodup covers the ~1e3 duplicated rows.

  pack_w<<<64, 256, 0, stream>>>(W1, w1t);
  pack_w<<<64, 256, 0, stream>>>(W2, w2t);

  mark_kernel<<<(NVOX+255)/256, 256, 0, stream>>>(indices, bits, dupbits, lin,
                                                  duplist, dupcount);
  scan1_kernel<<<128, 256, 0, stream>>>(bits, coarse, blockSums);
  scan2_kernel<<<1, 128, 0, stream>>>(blockSums, blockExcl);
  emit_kernel<<<NWORDS/256, 256, 0, stream>>>(bits, coarse, blockExcl, out_comb);
  zerodup_kernel<<<512, 256, 0, stream>>>(duplist, dupcount, lin, bits, coarse,
                                          blockExcl, out_merged);

  fused_mlp<<<(NVOX+63)/64, 256, 0, stream>>>(feats, w1t, g1, b1, w2t, g2, b2,
                                              y2, sq, NVOX);
  se_kernel<<<1, 128, 0, stream>>>(sq, sw1, sb1, sw2, sb2, scale);

  scatter_kernel<<<NVOX/4, 256, 0, stream>>>(y2, feats, scale, lin, bits, dupbits,
                                             coarse, blockExcl, out_merged, out_valid);
  dupfinal_kernel<<<512, 256, 0, stream>>>(duplist, dupcount, lin, dupbits, bits,
                                           coarse, blockExcl, out_merged, out_valid);
  padfill_kernel<<<512 + NVOX/4, 256, 0, stream>>>(blockExcl, out_merged,
                                                   out_comb, out_valid);
}

// Round 2
// 619.631 us; speedup vs baseline: 1.2857x; 1.0773x over previous
//
#include <hip/hip_runtime.h>
#include <cstdint>
#include <cstddef>

#define NVOX 300000
#define SB 4194304      // T*H*W = 2^22
#define ST 262144       // H*W   = 2^18
#define SHH 512         // W     = 2^9
#define SENT 33554432   // 2^25
#define NWORDS (SENT/64) // 524288 = 2^19

typedef __attribute__((ext_vector_type(8))) short short8;
typedef __attribute__((ext_vector_type(4))) float f32x4;

static __device__ __forceinline__ float bf2f(unsigned short u){
  return __uint_as_float(((unsigned)u) << 16);
}
static __device__ __forceinline__ unsigned short f2bf(float f){
  unsigned u = __float_as_uint(f);
  u = u + 0x7fffu + ((u >> 16) & 1u);
  return (unsigned short)(u >> 16);
}
static __device__ __forceinline__ short8 pack8(float4 a, float4 b){
  short8 s;
  s[0]=(short)f2bf(a.x); s[1]=(short)f2bf(a.y); s[2]=(short)f2bf(a.z); s[3]=(short)f2bf(a.w);
  s[4]=(short)f2bf(b.x); s[5]=(short)f2bf(b.y); s[6]=(short)f2bf(b.z); s[7]=(short)f2bf(b.w);
  return s;
}

// rank of a set bit = number of set bits before it (global, via scan structures)
static __device__ __forceinline__ unsigned rank_of(int l,
    const unsigned long long* __restrict__ bits,
    const unsigned* __restrict__ coarse,
    const unsigned* __restrict__ blockExcl){
  int w = l >> 6;
  unsigned long long m = 1ull << (l & 63);
  return coarse[w] + blockExcl[w >> 12]
       + (unsigned)__popcll(bits[w] & (m - 1ull));
}

// ---- pack W (fp32 KxN) -> fragment-contiguous bf16 layout ----
__global__ void pack_w(const float* __restrict__ W, unsigned short* __restrict__ Wt){
  int i = blockIdx.x*256 + threadIdx.x;  // 16384 elements
  int j = i & 7, lane = (i >> 3) & 63, ks = (i >> 9) & 3, nt = i >> 11;
  int k = ks*32 + (lane >> 4)*8 + j;
  int n = nt*16 + (lane & 15);
  Wt[i] = f2bf(W[k*128 + n]);
}

// ---------------- mark: compute lin, set presence bit, detect duplicates ----
__global__ void mark_kernel(const int* __restrict__ idx,
                            unsigned long long* __restrict__ bits,
                            unsigned long long* __restrict__ dupbits,
                            int* __restrict__ lin,
                            int* __restrict__ duplist,
                            int* __restrict__ dupcount){
  int i = blockIdx.x*256 + threadIdx.x;
  if(i >= NVOX) return;
  int4 v = ((const int4*)idx)[i];
  int l = v.x*SB + v.y*ST + v.z*SHH + v.w;
  lin[i] = l;
  unsigned long long m = 1ull << (l & 63);
  unsigned long long old = atomicOr(&bits[l >> 6], m);
  if(old & m){
    // secondary contributor to a duplicated lin: record it
    atomicOr(&dupbits[l >> 6], m);
    int s = atomicAdd(dupcount, 1);
    duplist[s] = i;
  }
}

// ---------------- scan of per-word popcounts ----------------
__global__ void scan1_kernel(const unsigned long long* __restrict__ bits,
                             unsigned* __restrict__ coarse,
                             unsigned* __restrict__ blockSums){
  __shared__ unsigned sh[256];
  int t = threadIdx.x, blk = blockIdx.x;
  int w0 = blk*4096 + t*16;
  unsigned p[16]; unsigned s = 0;
  #pragma unroll
  for(int k=0;k<16;k++){ unsigned c = (unsigned)__popcll(bits[w0+k]); p[k] = s; s += c; }
  sh[t] = s; __syncthreads();
  for(int off=1; off<256; off<<=1){
    unsigned v = (t >= off) ? sh[t-off] : 0u;
    __syncthreads();
    sh[t] += v;
    __syncthreads();
  }
  unsigned texcl = (t == 0) ? 0u : sh[t-1];
  #pragma unroll
  for(int k=0;k<16;k++) coarse[w0+k] = texcl + p[k];
  if(t == 255) blockSums[blk] = sh[255];
}

__global__ void scan2_kernel(const unsigned* __restrict__ blockSums,
                             unsigned* __restrict__ blockExcl){
  __shared__ unsigned sh[128];
  int t = threadIdx.x; // 128 threads
  sh[t] = blockSums[t]; __syncthreads();
  for(int off=1; off<128; off<<=1){
    unsigned v = (t >= off) ? sh[t-off] : 0u;
    __syncthreads();
    sh[t] += v;
    __syncthreads();
  }
  if(t == 0) blockExcl[0] = 0u;
  blockExcl[t+1] = sh[t];
}

// ---------------- emit comb_idx for real unique rows ----------------
__global__ void emit_kernel(const unsigned long long* __restrict__ bits,
                            const unsigned* __restrict__ coarse,
                            const unsigned* __restrict__ blockExcl,
                            float* __restrict__ out_comb){
  int w = blockIdx.x*256 + threadIdx.x;
  if(w >= NWORDS) return;
  unsigned long long bw = bits[w];
  if(!bw) return;
  unsigned j = coarse[w] + blockExcl[w >> 12];
  while(bw){
    int p = __builtin_ctzll(bw);
    bw &= bw - 1;
    int v = (w << 6) | p;
    int cb = v >> 22;
    int r  = v & (SB - 1);
    int ct = r >> 18;
    r &= (ST - 1);
    int ch = r >> 9;
    int cw = r & 511;
    ((float4*)out_comb)[j] = make_float4((float)cb,(float)ct,(float)ch,(float)cw);
    j++;
  }
}

// ---------------- zero accum rows of duplicated lins (pre-scatter) ---------
__global__ void zerodup_kernel(const int* __restrict__ duplist,
    const int* __restrict__ dupcount, const int* __restrict__ lin,
    const unsigned long long* __restrict__ bits,
    const unsigned* __restrict__ coarse, const unsigned* __restrict__ blockExcl,
    float* __restrict__ out_merged)
{
  int cnt = *dupcount;
  int lane = threadIdx.x & 63;
  for(int e = blockIdx.x*4 + (threadIdx.x >> 6); e < cnt; e += gridDim.x*4){
    int l = lin[duplist[e]];
    unsigned j = rank_of(l, bits, coarse, blockExcl);
    *(float2*)(out_merged + (size_t)j*128 + 2*lane) = make_float2(0.f, 0.f);
  }
}

// ---- fused MLP v3: X @ W1 -> LN -> ReLU -> @ W2 -> LN, MFMA bf16 ----------
// 256 thr = 4 waves; 128 rows/block, each wave owns TWO 16-row tiles (32 rows).
// W is staged in LDS once per block (phased W1 -> W2): B-frag reads become
// ds_read_b128 instead of per-wave L2 round trips (4x less global W traffic,
// 8 MFMA per B-frag group instead of 4).
#define MLP_ROWS 128
__global__ __launch_bounds__(256) void fused_mlp(
    const float* __restrict__ X,
    const unsigned short* __restrict__ w1t, const float* __restrict__ g1v,
    const float* __restrict__ b1v,
    const unsigned short* __restrict__ w2t, const float* __restrict__ g2v,
    const float* __restrict__ b2v,
    unsigned short* __restrict__ Y, float* __restrict__ sq, int nrows)
{
  __shared__ __align__(16) unsigned short wlds[16384];   // 32KB staged W
  __shared__ __align__(16) unsigned short xs[128][136];  // stride 272B
  __shared__ float sqs[4][128];                          // per-wave SE partials
  const int t = threadIdx.x;
  const int rowbase = blockIdx.x * MLP_ROWS;
  const int wave = t >> 6, quad = (t >> 4) & 3, l15 = t & 15;
  const int wbase = wave * 32;
  const int lane8 = (t & 63) * 8;   // short offset of this lane's B-frag
  const int kofs = quad * 8;
  const int grow0 = rowbase + wbase + l15;       // tile0 row
  const int grow1 = grow0 + 16;                  // tile1 row
  const bool rv0 = grow0 < nrows, rv1 = grow1 < nrows;

  // stage W1 -> LDS (coalesced float4; 32KB / 256thr = 8 iters)
  #pragma unroll
  for (int m = 0; m < 8; m++)
    ((float4*)wlds)[m*256 + t] = ((const float4*)w1t)[m*256 + t];

  // direct A-frag loads for both tiles (issue while W1 stage is in flight)
  short8 a0,a1,a2,a3,a4,a5,a6,a7;
  {
    float4 z = make_float4(0.f,0.f,0.f,0.f);
    float4 u0=z,u1=z,u2=z,u3=z,u4=z,u5=z,u6=z,u7=z;
    float4 w0=z,w1=z,w2=z,w3=z,w4=z,w5=z,w6=z,w7=z;
    if (rv0) {
      const float* xp = X + (size_t)grow0 * 128 + kofs;
      u0 = ((const float4*)(xp      ))[0];
      u1 = ((const float4*)(xp +   4))[0];
      u2 = ((const float4*)(xp +  32))[0];
      u3 = ((const float4*)(xp +  36))[0];
      u4 = ((const float4*)(xp +  64))[0];
      u5 = ((const float4*)(xp +  68))[0];
      u6 = ((const float4*)(xp +  96))[0];
      u7 = ((const float4*)(xp + 100))[0];
    }
    if (rv1) {
      const float* xp = X + (size_t)grow1 * 128 + kofs;
      w0 = ((const float4*)(xp      ))[0];
      w1 = ((const float4*)(xp +   4))[0];
      w2 = ((const float4*)(xp +  32))[0];
      w3 = ((const float4*)(xp +  36))[0];
      w4 = ((const float4*)(xp +  64))[0];
      w5 = ((const float4*)(xp +  68))[0];
      w6 = ((const float4*)(xp +  96))[0];
      w7 = ((const float4*)(xp + 100))[0];
    }
    a0 = pack8(u0, u1); a1 = pack8(u2, u3);
    a2 = pack8(u4, u5); a3 = pack8(u6, u7);
    a4 = pack8(w0, w1); a5 = pack8(w2, w3);
    a6 = pack8(w4, w5); a7 = pack8(w6, w7);
  }
  __syncthreads();   // W1 resident

  // ================= GEMM1 + LN1 + ReLU (both tiles) =================
  {
    f32x4 acc0[8], acc1[8];
    #pragma unroll
    for (int nt = 0; nt < 8; nt++) {
      const unsigned short* wp = wlds + nt*2048 + lane8;
      short8 bv0 = *(const short8*)(wp);
      short8 bv1 = *(const short8*)(wp + 512);
      short8 bv2 = *(const short8*)(wp + 1024);
      short8 bv3 = *(const short8*)(wp + 1536);
      f32x4 c0 = {0.f,0.f,0.f,0.f}, c1 = {0.f,0.f,0.f,0.f};
      c0 = __builtin_amdgcn_mfma_f32_16x16x32_bf16(a0, bv0, c0, 0, 0, 0);
      c1 = __builtin_amdgcn_mfma_f32_16x16x32_bf16(a4, bv0, c1, 0, 0, 0);
      c0 = __builtin_amdgcn_mfma_f32_16x16x32_bf16(a1, bv1, c0, 0, 0, 0);
      c1 = __builtin_amdgcn_mfma_f32_16x16x32_bf16(a5, bv1, c1, 0, 0, 0);
      c0 = __builtin_amdgcn_mfma_f32_16x16x32_bf16(a2, bv2, c0, 0, 0, 0);
      c1 = __builtin_amdgcn_mfma_f32_16x16x32_bf16(a6, bv2, c1, 0, 0, 0);
      c0 = __builtin_amdgcn_mfma_f32_16x16x32_bf16(a3, bv3, c0, 0, 0, 0);
      c1 = __builtin_amdgcn_mfma_f32_16x16x32_bf16(a7, bv3, c1, 0, 0, 0);
      acc0[nt] = c0; acc1[nt] = c1;
    }

    float gg[8], bb[8];
    #pragma unroll
    for (int nt = 0; nt < 8; nt++) {
      gg[nt] = g1v[nt*16 + l15]; bb[nt] = b1v[nt*16 + l15];
    }
    #pragma unroll
    for (int tile = 0; tile < 2; tile++) {
      #pragma unroll
      for (int r = 0; r < 4; r++) {
        float s = 0.f, q = 0.f;
        #pragma unroll
        for (int nt = 0; nt < 8; nt++) {
          float v = tile ? acc1[nt][r] : acc0[nt][r]; s += v; q += v*v;
        }
        #pragma unroll
        for (int mm = 1; mm < 16; mm <<= 1) { s += __shfl_xor(s, mm); q += __shfl_xor(q, mm); }
        float mu = s * (1.f/128.f);
        float var = fmaxf(q * (1.f/128.f) - mu*mu, 0.f);
        float rinv = rsqrtf(var + 1e-5f);
        int orow = wbase + tile*16 + quad*4 + r;
        #pragma unroll
        for (int nt = 0; nt < 8; nt++) {
          float v = ((tile ? acc1[nt][r] : acc0[nt][r]) - mu) * rinv * gg[nt] + bb[nt];
          v = fmaxf(v, 0.f);
          xs[orow][nt*16 + l15] = f2bf(v);   // wave-private rows: no barrier
        }
      }
    }
  }
  __syncthreads();   // all waves done reading W1 from wlds

  // stage W2 -> LDS
  #pragma unroll
  for (int m = 0; m < 8; m++)
    ((float4*)wlds)[m*256 + t] = ((const float4*)w2t)[m*256 + t];

  // GEMM2 A-frags from xs (wave-private rows; overlaps W2 stage)
  short8 p0 = *(const short8*)&xs[wbase + l15][  0 + kofs];
  short8 p1 = *(const short8*)&xs[wbase + l15][ 32 + kofs];
  short8 p2 = *(const short8*)&xs[wbase + l15][ 64 + kofs];
  short8 p3 = *(const short8*)&xs[wbase + l15][ 96 + kofs];
  short8 p4 = *(const short8*)&xs[wbase + 16 + l15][  0 + kofs];
  short8 p5 = *(const short8*)&xs[wbase + 16 + l15][ 32 + kofs];
  short8 p6 = *(const short8*)&xs[wbase + 16 + l15][ 64 + kofs];
  short8 p7 = *(const short8*)&xs[wbase + 16 + l15][ 96 + kofs];
  __syncthreads();   // W2 resident

  // ================= GEMM2 + LN2 + SE partial sums =================
  {
    f32x4 acc0[8], acc1[8];
    #pragma unroll
    for (int nt = 0; nt < 8; nt++) {
      const unsigned short* wp = wlds + nt*2048 + lane8;
      short8 bv0 = *(const short8*)(wp);
      short8 bv1 = *(const short8*)(wp + 512);
      short8 bv2 = *(const short8*)(wp + 1024);
      short8 bv3 = *(const short8*)(wp + 1536);
      f32x4 c0 = {0.f,0.f,0.f,0.f}, c1 = {0.f,0.f,0.f,0.f};
      c0 = __builtin_amdgcn_mfma_f32_16x16x32_bf16(p0, bv0, c0, 0, 0, 0);
      c1 = __builtin_amdgcn_mfma_f32_16x16x32_bf16(p4, bv0, c1, 0, 0, 0);
      c0 = __builtin_amdgcn_mfma_f32_16x16x32_bf16(p1, bv1, c0, 0, 0, 0);
      c1 = __builtin_amdgcn_mfma_f32_16x16x32_bf16(p5, bv1, c1, 0, 0, 0);
      c0 = __builtin_amdgcn_mfma_f32_16x16x32_bf16(p2, bv2, c0, 0, 0, 0);
      c1 = __builtin_amdgcn_mfma_f32_16x16x32_bf16(p6, bv2, c1, 0, 0, 0);
      c0 = __builtin_amdgcn_mfma_f32_16x16x32_bf16(p3, bv3, c0, 0, 0, 0);
      c1 = __builtin_amdgcn_mfma_f32_16x16x32_bf16(p7, bv3, c1, 0, 0, 0);
      acc0[nt] = c0; acc1[nt] = c1;
    }

    float gg[8], bb[8], ch[8];
    #pragma unroll
    for (int nt = 0; nt < 8; nt++) {
      gg[nt] = g2v[nt*16 + l15]; bb[nt] = b2v[nt*16 + l15]; ch[nt] = 0.f;
    }
    #pragma unroll
    for (int tile = 0; tile < 2; tile++) {
      #pragma unroll
      for (int r = 0; r < 4; r++) {
        float s = 0.f, q = 0.f;
        #pragma unroll
        for (int nt = 0; nt < 8; nt++) {
          float v = tile ? acc1[nt][r] : acc0[nt][r]; s += v; q += v*v;
        }
        #pragma unroll
        for (int mm = 1; mm < 16; mm <<= 1) { s += __shfl_xor(s, mm); q += __shfl_xor(q, mm); }
        float mu = s * (1.f/128.f);
        float var = fmaxf(q * (1.f/128.f) - mu*mu, 0.f);
        float rinv = rsqrtf(var + 1e-5f);
        int orow = wbase + tile*16 + quad*4 + r;
        bool rv = (rowbase + orow) < nrows;
        #pragma unroll
        for (int nt = 0; nt < 8; nt++) {
          float v = ((tile ? acc1[nt][r] : acc0[nt][r]) - mu) * rinv * gg[nt] + bb[nt];
          if (rv) ch[nt] += v;
          xs[orow][nt*16 + l15] = f2bf(v);
        }
      }
    }
    // SE channel partials: reduce across quads, plain store to per-wave bank
    #pragma unroll
    for (int nt = 0; nt < 8; nt++) {
      float v = ch[nt];
      v += __shfl_xor(v, 16); v += __shfl_xor(v, 32);
      if (quad == 0) sqs[wave][nt*16 + l15] = v;
    }
  }

  // per-wave output store: each wave stores its own 32 xs rows (no barrier)
  #pragma unroll
  for (int mm = 0; mm < 8; mm++) {
    int c = mm*64 + (t & 63);       // 512 chunks of 8 shorts = 32 rows x 16
    int rl = wbase + (c >> 4), s8 = c & 15;
    if (rowbase + rl < nrows) {
      short8 v = *(const short8*)&xs[rl][s8*8];
      *(short8*)(Y + (size_t)(rowbase+rl)*128 + s8*8) = v;
    }
  }
  __syncthreads();
  if (t < 128) atomicAdd(&sq[t], sqs[0][t] + sqs[1][t] + sqs[2][t] + sqs[3][t]);
}

// ---------------- SE: mean -> fc -> relu -> fc -> sigmoid ----------------
__global__ void se_kernel(const float* __restrict__ sq, const float* __restrict__ w1,
    const float* __restrict__ b1, const float* __restrict__ w2,
    const float* __restrict__ b2, float* __restrict__ scale)
{
  __shared__ float mean[128];
  __shared__ float h1[32];
  int t = threadIdx.x; // 128 threads
  mean[t] = sq[t] * (1.f/(float)NVOX);
  __syncthreads();
  if(t < 32){
    float s = b1[t];
    for(int c=0;c<128;c++) s += mean[c]*w1[c*32+t];
    h1[t] = fmaxf(s, 0.f);
  }
  __syncthreads();
  float s = b2[t];
  for(int j=0;j<32;j++) s += h1[j]*w2[j*128+t];
  scale[t] = 1.f/(1.f + expf(-s));
}

// ---- scatter v2: unique rows -> fused relu/valid + PLAIN stores (no atomics,
// no finalize pass); duplicated rows (~1e-3 of rows) -> atomicAdd raw sums ----
__global__ void scatter_kernel(const unsigned short* __restrict__ y2,
    const float* __restrict__ feats, const float* __restrict__ scale,
    const int* __restrict__ lin, const unsigned long long* __restrict__ bits,
    const unsigned long long* __restrict__ dupbits,
    const unsigned* __restrict__ coarse, const unsigned* __restrict__ blockExcl,
    float* __restrict__ out_merged, float* __restrict__ out_valid)
{
  int row = blockIdx.x*4 + (threadIdx.x >> 6);
  int lane = threadIdx.x & 63;
  int l = lin[row];
  int w = l >> 6;
  unsigned long long m = 1ull << (l & 63);
  unsigned j = coarse[w] + blockExcl[w >> 12]
             + (unsigned)__popcll(bits[w] & (m - 1ull));
  size_t rb = (size_t)row * 128;
  unsigned yy = *(const unsigned*)(y2 + rb + 2*lane);
  float2 ff = *(const float2*)(feats + rb + 2*lane);
  float2 ss = *(const float2*)(scale + 2*lane);
  float v0 = bf2f((unsigned short)(yy & 0xffffu)) * ss.x + ff.x;
  float v1 = bf2f((unsigned short)(yy >> 16))     * ss.y + ff.y;
  size_t ob = (size_t)j * 128;
  if (dupbits[w] & m) {           // wave-uniform branch (per-row condition)
    atomicAdd(out_merged + ob + 2*lane,     v0);
    atomicAdd(out_merged + ob + 2*lane + 1, v1);
  } else {
    float s = fabsf(v0) + fabsf(v1);
    #pragma unroll
    for(int mm=1; mm<64; mm<<=1) s += __shfl_xor(s, mm);
    bool valid = s > 1e-8f;
    float2 o;
    o.x = valid ? fmaxf(v0, 0.f) : 0.f;
    o.y = valid ? fmaxf(v1, 0.f) : 0.f;
    *(float2*)(out_merged + ob + 2*lane) = o;
    if (lane == 0) out_valid[j] = valid ? 1.f : 0.f;
  }
}

// ---------------- finalize only the duplicated rows (claim via dupbits) ----
__global__ void dupfinal_kernel(const int* __restrict__ duplist,
    const int* __restrict__ dupcount, const int* __restrict__ lin,
    unsigned long long* __restrict__ dupbits,
    const unsigned long long* __restrict__ bits,
    const unsigned* __restrict__ coarse, const unsigned* __restrict__ blockExcl,
    float* __restrict__ out_merged, float* __restrict__ out_valid)
{
  int cnt = *dupcount;
  int lane = threadIdx.x & 63;
  for(int e = blockIdx.x*4 + (threadIdx.x >> 6); e < cnt; e += gridDim.x*4){
    int l = lin[duplist[e]];
    int w = l >> 6;
    unsigned long long m = 1ull << (l & 63);
    int claimed = 0;
    if (lane == 0){
      unsigned long long old = atomicAnd(&dupbits[w], ~m);
      claimed = (old & m) ? 1 : 0;
    }
    claimed = __shfl(claimed, 0);
    if (!claimed) continue;       // another entry with the same lin owns it
    unsigned j = coarse[w] + blockExcl[w >> 12]
               + (unsigned)__popcll(bits[w] & (m - 1ull));
    size_t ob = (size_t)j * 128;
    float2 v = *(float2*)(out_merged + ob + 2*lane);
    float s = fabsf(v.x) + fabsf(v.y);
    #pragma unroll
    for(int mm=1; mm<64; mm<<=1) s += __shfl_xor(s, mm);
    bool valid = s > 1e-8f;
    float2 o;
    o.x = valid ? fmaxf(v.x, 0.f) : 0.f;
    o.y = valid ? fmaxf(v.y, 0.f) : 0.f;
    *(float2*)(out_merged + ob + 2*lane) = o;
    if (lane == 0) out_valid[j] = valid ? 1.f : 0.f;
  }
}

// ---------------- pad rows [U, 2N): zeros + sentinel comb + valid=0 --------
// blocks [0,512): grid-stride over [U, NVOX) (tiny: N - U == #dups)
// blocks [512, 512+NVOX/4): unconditional rows [NVOX, 2*NVOX)
__global__ void padfill_kernel(const unsigned* __restrict__ blockExcl,
    float* __restrict__ out_merged, float* __restrict__ out_comb,
    float* __restrict__ out_valid)
{
  int lane = threadIdx.x & 63;
  int wv = threadIdx.x >> 6;
  if (blockIdx.x < 512) {
    unsigned U = blockExcl[128];
    for (unsigned r = U + blockIdx.x*4 + wv; r < NVOX; r += 512*4) {
      *(float2*)(out_merged + (size_t)r*128 + 2*lane) = make_float2(0.f, 0.f);
      if (lane == 0) {
        out_valid[r] = 0.f;
        ((float4*)out_comb)[r] = make_float4(8.f, 0.f, 0.f, 0.f);
      }
    }
  } else {
    int r = NVOX + (blockIdx.x - 512)*4 + wv;
    *(float2*)(out_merged + (size_t)r*128 + 2*lane) = make_float2(0.f, 0.f);
    if (lane == 0) {
      out_valid[r] = 0.f;
      ((float4*)out_comb)[r] = make_float4(8.f, 0.f, 0.f, 0.f);
    }
  }
}

extern "C" void kernel_launch(void* const* d_in, const int* in_sizes, int n_in,
                              void* d_out, int out_size, void* d_ws, size_t ws_size,
                              hipStream_t stream)
{
  const float* feats   = (const float*)d_in[0];
  const int*   indices = (const int*)d_in[1];
  const float* W1  = (const float*)d_in[2];
  const float* g1  = (const float*)d_in[3];
  const float* b1  = (const float*)d_in[4];
  const float* W2  = (const float*)d_in[5];
  const float* g2  = (const float*)d_in[6];
  const float* b2  = (const float*)d_in[7];
  const float* sw1 = (const float*)d_in[8];
  const float* sb1 = (const float*)d_in[9];
  const float* sw2 = (const float*)d_in[10];
  const float* sb2 = (const float*)d_in[11];

  float* out_merged = (float*)d_out;                        // [2N,128]
  float* out_comb   = out_merged + (size_t)2*NVOX*128;      // [2N,4]
  float* out_valid  = out_comb   + (size_t)2*NVOX*4;        // [2N]

  char* cur = (char*)d_ws;
  auto alloc = [&](size_t b) -> void* {
    void* p = (void*)cur;
    cur += (b + 255) & ~(size_t)255;
    return p;
  };
  unsigned short*      y2        = (unsigned short*)alloc((size_t)NVOX*128*2);
  unsigned long long*  bits      = (unsigned long long*)alloc((size_t)NWORDS*8);
  unsigned long long*  dupbits   = (unsigned long long*)alloc((size_t)NWORDS*8); // contiguous w/ bits
  unsigned*            coarse    = (unsigned*)alloc((size_t)NWORDS*4);
  unsigned*            blockSums = (unsigned*)alloc(128*4);
  unsigned*            blockExcl = (unsigned*)alloc(129*4);
  float*               sq        = (float*)alloc(128*4);
  int*                 dupcount  = (int*)alloc(4);          // contiguous w/ sq
  float*               scale     = (float*)alloc(128*4);
  int*                 lin       = (int*)alloc((size_t)NVOX*4);
  int*                 duplist   = (int*)alloc((size_t)NVOX*4);
  unsigned short*      w1t       = (unsigned short*)alloc(128*128*2);
  unsigned short*      w2t       = (unsigned short*)alloc(128*128*2);

  // bits + dupbits are adjacent 256-aligned 4MB blocks -> one 8MB clear
  hipMemsetAsync(bits, 0, (size_t)NWORDS*8*2, stream);
  // sq (512B) + dupcount (256B slot) adjacent -> one clear
  hipMemsetAsync(sq, 0, 512 + 256, stream);

  pack_w<<<64, 256, 0, stream>>>(W1, w1t);
  pack_w<<<64, 256, 0, stream>>>(W2, w2t);

  mark_kernel<<<(NVOX+255)/256, 256, 0, stream>>>(indices, bits, dupbits, lin,
                                                  duplist, dupcount);
  scan1_kernel<<<128, 256, 0, stream>>>(bits, coarse, blockSums);
  scan2_kernel<<<1, 128, 0, stream>>>(blockSums, blockExcl);
  emit_kernel<<<NWORDS/256, 256, 0, stream>>>(bits, coarse, blockExcl, out_comb);
  zerodup_kernel<<<512, 256, 0, stream>>>(duplist, dupcount, lin, bits, coarse,
                                          blockExcl, out_merged);

  fused_mlp<<<(NVOX + MLP_ROWS - 1)/MLP_ROWS, 256, 0, stream>>>(
      feats, w1t, g1, b1, w2t, g2, b2, y2, sq, NVOX);
  se_kernel<<<1, 128, 0, stream>>>(sq, sw1, sb1, sw2, sb2, scale);

  scatter_kernel<<<NVOX/4, 256, 0, stream>>>(y2, feats, scale, lin, bits, dupbits,
                                             coarse, blockExcl, out_merged, out_valid);
  dupfinal_kernel<<<512, 256, 0, stream>>>(duplist, dupcount, lin, dupbits, bits,
                                           coarse, blockExcl, out_merged, out_valid);
  padfill_kernel<<<512 + NVOX/4, 256, 0, stream>>>(blockExcl, out_merged,
                                                   out_comb, out_valid);
}

// Round 3
// 612.901 us; speedup vs baseline: 1.2998x; 1.0110x over previous
//
#include <hip/hip_runtime.h>
#include <cstdint>
#include <cstddef>

#define NVOX 300000
#define SB 4194304      // T*H*W = 2^22
#define ST 262144       // H*W   = 2^18
#define SHH 512         // W     = 2^9
#define SENT 33554432   // 2^25
#define NWORDS (SENT/64) // 524288 = 2^19
#define SQB 32           // SE partial-sum buckets

typedef __attribute__((ext_vector_type(8))) short short8;
typedef __attribute__((ext_vector_type(4))) float f32x4;

// RNE float->bf16 via compiler (__bf16 lowers to v_cvt_pk_bf16_f32 on gfx950;
// identical rounding to the previous bit-twiddle, ~4x fewer VALU ops)
static __device__ __forceinline__ unsigned short f2bf(float f){
  union { __bf16 b; unsigned short u; } c;
  c.b = (__bf16)f;
  return c.u;
}
static __device__ __forceinline__ float bf2f(unsigned short u){
  return __uint_as_float(((unsigned)u) << 16);
}
static __device__ __forceinline__ short8 pack8(float4 a, float4 b){
  short8 s;
  s[0]=(short)f2bf(a.x); s[1]=(short)f2bf(a.y); s[2]=(short)f2bf(a.z); s[3]=(short)f2bf(a.w);
  s[4]=(short)f2bf(b.x); s[5]=(short)f2bf(b.y); s[6]=(short)f2bf(b.z); s[7]=(short)f2bf(b.w);
  return s;
}

// rank of a set bit = number of set bits before it (global, via scan structures)
static __device__ __forceinline__ unsigned rank_of(int l,
    const unsigned long long* __restrict__ bits,
    const unsigned* __restrict__ coarse,
    const unsigned* __restrict__ blockExcl){
  int w = l >> 6;
  unsigned long long m = 1ull << (l & 63);
  return coarse[w] + blockExcl[w >> 12]
       + (unsigned)__popcll(bits[w] & (m - 1ull));
}

// ---- pack W1+W2 (fp32 KxN) -> fragment-contiguous bf16 layout (one launch) ----
__global__ void pack_w2(const float* __restrict__ W1, const float* __restrict__ W2,
                        unsigned short* __restrict__ W1t, unsigned short* __restrict__ W2t){
  int gi = blockIdx.x*256 + threadIdx.x;      // 2 x 16384 elements
  const float* W = (gi < 16384) ? W1 : W2;
  unsigned short* Wt = (gi < 16384) ? W1t : W2t;
  int i = gi & 16383;
  int j = i & 7, lane = (i >> 3) & 63, ks = (i >> 9) & 3, nt = i >> 11;
  int k = ks*32 + (lane >> 4)*8 + j;
  int n = nt*16 + (lane & 15);
  Wt[i] = f2bf(W[k*128 + n]);
}

// ---------------- mark: compute lin, set presence bit, detect duplicates ----
__global__ void mark_kernel(const int* __restrict__ idx,
                            unsigned long long* __restrict__ bits,
                            unsigned long long* __restrict__ dupbits,
                            int* __restrict__ lin,
                            int* __restrict__ duplist,
                            int* __restrict__ dupcount){
  int i = blockIdx.x*256 + threadIdx.x;
  if(i >= NVOX) return;
  int4 v = ((const int4*)idx)[i];
  int l = v.x*SB + v.y*ST + v.z*SHH + v.w;
  lin[i] = l;
  unsigned long long m = 1ull << (l & 63);
  unsigned long long old = atomicOr(&bits[l >> 6], m);
  if(old & m){
    atomicOr(&dupbits[l >> 6], m);
    int s = atomicAdd(dupcount, 1);
    duplist[s] = i;
  }
}

// ---------------- scan of per-word popcounts ----------------
__global__ void scan1_kernel(const unsigned long long* __restrict__ bits,
                             unsigned* __restrict__ coarse,
                             unsigned* __restrict__ blockSums){
  __shared__ unsigned sh[256];
  int t = threadIdx.x, blk = blockIdx.x;
  int w0 = blk*4096 + t*16;
  unsigned p[16]; unsigned s = 0;
  #pragma unroll
  for(int k=0;k<16;k++){ unsigned c = (unsigned)__popcll(bits[w0+k]); p[k] = s; s += c; }
  sh[t] = s; __syncthreads();
  for(int off=1; off<256; off<<=1){
    unsigned v = (t >= off) ? sh[t-off] : 0u;
    __syncthreads();
    sh[t] += v;
    __syncthreads();
  }
  unsigned texcl = (t == 0) ? 0u : sh[t-1];
  #pragma unroll
  for(int k=0;k<16;k++) coarse[w0+k] = texcl + p[k];
  if(t == 255) blockSums[blk] = sh[255];
}

__global__ void scan2_kernel(const unsigned* __restrict__ blockSums,
                             unsigned* __restrict__ blockExcl){
  __shared__ unsigned sh[128];
  int t = threadIdx.x; // 128 threads
  sh[t] = blockSums[t]; __syncthreads();
  for(int off=1; off<128; off<<=1){
    unsigned v = (t >= off) ? sh[t-off] : 0u;
    __syncthreads();
    sh[t] += v;
    __syncthreads();
  }
  if(t == 0) blockExcl[0] = 0u;
  blockExcl[t+1] = sh[t];
}

// ------- emit comb_idx for real unique rows + zero dup accum rows ----------
// blocks [0,2048): emit; blocks [2048,2560): zerodup (grid-stride)
__global__ void emit_zerodup_kernel(const unsigned long long* __restrict__ bits,
                            const unsigned* __restrict__ coarse,
                            const unsigned* __restrict__ blockExcl,
                            float* __restrict__ out_comb,
                            const int* __restrict__ duplist,
                            const int* __restrict__ dupcount,
                            const int* __restrict__ lin,
                            float* __restrict__ out_merged){
  if (blockIdx.x < 2048) {
    int w = blockIdx.x*256 + threadIdx.x;
    unsigned long long bw = bits[w];
    if(!bw) return;
    unsigned j = coarse[w] + blockExcl[w >> 12];
    while(bw){
      int p = __builtin_ctzll(bw);
      bw &= bw - 1;
      int v = (w << 6) | p;
      int cb = v >> 22;
      int r  = v & (SB - 1);
      int ct = r >> 18;
      r &= (ST - 1);
      int ch = r >> 9;
      int cw = r & 511;
      ((float4*)out_comb)[j] = make_float4((float)cb,(float)ct,(float)ch,(float)cw);
      j++;
    }
  } else {
    int cnt = *dupcount;
    int lane = threadIdx.x & 63;
    int base = (blockIdx.x - 2048)*4 + (threadIdx.x >> 6);
    for(int e = base; e < cnt; e += 512*4){
      int l = lin[duplist[e]];
      unsigned j = rank_of(l, bits, coarse, blockExcl);
      *(float2*)(out_merged + (size_t)j*128 + 2*lane) = make_float2(0.f, 0.f);
    }
  }
}

// ---- fused MLP v4: X @ W1 -> LN -> ReLU -> @ W2 -> LN, MFMA bf16 ----------
// 256 thr = 4 waves; 128 rows/block, each wave owns TWO 16-row tiles.
// v4: cvt_pk bf16 conversions, W2 prefetched to regs at start (mid-kernel
// stage is pure ds_write), SE partials to 32 contention-buckets.
#define MLP_ROWS 128
__global__ __launch_bounds__(256) void fused_mlp(
    const float* __restrict__ X,
    const unsigned short* __restrict__ w1t, const float* __restrict__ g1v,
    const float* __restrict__ b1v,
    const unsigned short* __restrict__ w2t, const float* __restrict__ g2v,
    const float* __restrict__ b2v,
    unsigned short* __restrict__ Y, float* __restrict__ sqb, int nrows)
{
  __shared__ __align__(16) unsigned short wlds[16384];   // 32KB staged W
  __shared__ __align__(16) unsigned short xs[128][136];  // stride 272B
  __shared__ float sqs[4][128];                          // per-wave SE partials
  const int t = threadIdx.x;
  const int rowbase = blockIdx.x * MLP_ROWS;
  const int wave = t >> 6, quad = (t >> 4) & 3, l15 = t & 15;
  const int wbase = wave * 32;
  const int lane8 = (t & 63) * 8;   // short offset of this lane's B-frag
  const int kofs = quad * 8;
  const int grow0 = rowbase + wbase + l15;       // tile0 row
  const int grow1 = grow0 + 16;                  // tile1 row
  const bool rv0 = grow0 < nrows, rv1 = grow1 < nrows;

  // stage W1 -> LDS (coalesced float4; 32KB / 256thr = 8 iters)
  #pragma unroll
  for (int m = 0; m < 8; m++)
    ((float4*)wlds)[m*256 + t] = ((const float4*)w1t)[m*256 + t];

  // prefetch W2 into registers (stored to LDS after GEMM1; hides the global
  // latency that used to sit between two barriers mid-kernel)
  float4 wreg[8];
  #pragma unroll
  for (int m = 0; m < 8; m++)
    wreg[m] = ((const float4*)w2t)[m*256 + t];

  // direct A-frag loads for both tiles (issue while W stages are in flight)
  short8 a0,a1,a2,a3,a4,a5,a6,a7;
  {
    float4 z = make_float4(0.f,0.f,0.f,0.f);
    float4 u0=z,u1=z,u2=z,u3=z,u4=z,u5=z,u6=z,u7=z;
    float4 w0=z,w1=z,w2=z,w3=z,w4=z,w5=z,w6=z,w7=z;
    if (rv0) {
      const float* xp = X + (size_t)grow0 * 128 + kofs;
      u0 = ((const float4*)(xp      ))[0];
      u1 = ((const float4*)(xp +   4))[0];
      u2 = ((const float4*)(xp +  32))[0];
      u3 = ((const float4*)(xp +  36))[0];
      u4 = ((const float4*)(xp +  64))[0];
      u5 = ((const float4*)(xp +  68))[0];
      u6 = ((const float4*)(xp +  96))[0];
      u7 = ((const float4*)(xp + 100))[0];
    }
    if (rv1) {
      const float* xp = X + (size_t)grow1 * 128 + kofs;
      w0 = ((const float4*)(xp      ))[0];
      w1 = ((const float4*)(xp +   4))[0];
      w2 = ((const float4*)(xp +  32))[0];
      w3 = ((const float4*)(xp +  36))[0];
      w4 = ((const float4*)(xp +  64))[0];
      w5 = ((const float4*)(xp +  68))[0];
      w6 = ((const float4*)(xp +  96))[0];
      w7 = ((const float4*)(xp + 100))[0];
    }
    a0 = pack8(u0, u1); a1 = pack8(u2, u3);
    a2 = pack8(u4, u5); a3 = pack8(u6, u7);
    a4 = pack8(w0, w1); a5 = pack8(w2, w3);
    a6 = pack8(w4, w5); a7 = pack8(w6, w7);
  }
  __syncthreads();   // W1 resident

  // ================= GEMM1 + LN1 + ReLU (both tiles) =================
  {
    f32x4 acc0[8], acc1[8];
    #pragma unroll
    for (int nt = 0; nt < 8; nt++) {
      const unsigned short* wp = wlds + nt*2048 + lane8;
      short8 bv0 = *(const short8*)(wp);
      short8 bv1 = *(const short8*)(wp + 512);
      short8 bv2 = *(const short8*)(wp + 1024);
      short8 bv3 = *(const short8*)(wp + 1536);
      f32x4 c0 = {0.f,0.f,0.f,0.f}, c1 = {0.f,0.f,0.f,0.f};
      c0 = __builtin_amdgcn_mfma_f32_16x16x32_bf16(a0, bv0, c0, 0, 0, 0);
      c1 = __builtin_amdgcn_mfma_f32_16x16x32_bf16(a4, bv0, c1, 0, 0, 0);
      c0 = __builtin_amdgcn_mfma_f32_16x16x32_bf16(a1, bv1, c0, 0, 0, 0);
      c1 = __builtin_amdgcn_mfma_f32_16x16x32_bf16(a5, bv1, c1, 0, 0, 0);
      c0 = __builtin_amdgcn_mfma_f32_16x16x32_bf16(a2, bv2, c0, 0, 0, 0);
      c1 = __builtin_amdgcn_mfma_f32_16x16x32_bf16(a6, bv2, c1, 0, 0, 0);
      c0 = __builtin_amdgcn_mfma_f32_16x16x32_bf16(a3, bv3, c0, 0, 0, 0);
      c1 = __builtin_amdgcn_mfma_f32_16x16x32_bf16(a7, bv3, c1, 0, 0, 0);
      acc0[nt] = c0; acc1[nt] = c1;
    }

    float gg[8], bb[8];
    #pragma unroll
    for (int nt = 0; nt < 8; nt++) {
      gg[nt] = g1v[nt*16 + l15]; bb[nt] = b1v[nt*16 + l15];
    }
    #pragma unroll
    for (int tile = 0; tile < 2; tile++) {
      #pragma unroll
      for (int r = 0; r < 4; r++) {
        float s = 0.f, q = 0.f;
        #pragma unroll
        for (int nt = 0; nt < 8; nt++) {
          float v = tile ? acc1[nt][r] : acc0[nt][r]; s += v; q += v*v;
        }
        #pragma unroll
        for (int mm = 1; mm < 16; mm <<= 1) { s += __shfl_xor(s, mm); q += __shfl_xor(q, mm); }
        float mu = s * (1.f/128.f);
        float var = fmaxf(q * (1.f/128.f) - mu*mu, 0.f);
        float rinv = rsqrtf(var + 1e-5f);
        int orow = wbase + tile*16 + quad*4 + r;
        #pragma unroll
        for (int nt = 0; nt < 8; nt++) {
          float v = ((tile ? acc1[nt][r] : acc0[nt][r]) - mu) * rinv * gg[nt] + bb[nt];
          v = fmaxf(v, 0.f);
          xs[orow][nt*16 + l15] = f2bf(v);   // wave-private rows: no barrier
        }
      }
    }
  }
  __syncthreads();   // all waves done reading W1 from wlds

  // stage W2 -> LDS from prefetched registers (no global latency here)
  #pragma unroll
  for (int m = 0; m < 8; m++)
    ((float4*)wlds)[m*256 + t] = wreg[m];

  // GEMM2 A-frags from xs (wave-private rows; overlaps W2 ds_writes)
  short8 p0 = *(const short8*)&xs[wbase + l15][  0 + kofs];
  short8 p1 = *(const short8*)&xs[wbase + l15][ 32 + kofs];
  short8 p2 = *(const short8*)&xs[wbase + l15][ 64 + kofs];
  short8 p3 = *(const short8*)&xs[wbase + l15][ 96 + kofs];
  short8 p4 = *(const short8*)&xs[wbase + 16 + l15][  0 + kofs];
  short8 p5 = *(const short8*)&xs[wbase + 16 + l15][ 32 + kofs];
  short8 p6 = *(const short8*)&xs[wbase + 16 + l15][ 64 + kofs];
  short8 p7 = *(const short8*)&xs[wbase + 16 + l15][ 96 + kofs];
  __syncthreads();   // W2 resident

  // ================= GEMM2 + LN2 + SE partial sums =================
  {
    f32x4 acc0[8], acc1[8];
    #pragma unroll
    for (int nt = 0; nt < 8; nt++) {
      const unsigned short* wp = wlds + nt*2048 + lane8;
      short8 bv0 = *(const short8*)(wp);
      short8 bv1 = *(const short8*)(wp + 512);
      short8 bv2 = *(const short8*)(wp + 1024);
      short8 bv3 = *(const short8*)(wp + 1536);
      f32x4 c0 = {0.f,0.f,0.f,0.f}, c1 = {0.f,0.f,0.f,0.f};
      c0 = __builtin_amdgcn_mfma_f32_16x16x32_bf16(p0, bv0, c0, 0, 0, 0);
      c1 = __builtin_amdgcn_mfma_f32_16x16x32_bf16(p4, bv0, c1, 0, 0, 0);
      c0 = __builtin_amdgcn_mfma_f32_16x16x32_bf16(p1, bv1, c0, 0, 0, 0);
      c1 = __builtin_amdgcn_mfma_f32_16x16x32_bf16(p5, bv1, c1, 0, 0, 0);
      c0 = __builtin_amdgcn_mfma_f32_16x16x32_bf16(p2, bv2, c0, 0, 0, 0);
      c1 = __builtin_amdgcn_mfma_f32_16x16x32_bf16(p6, bv2, c1, 0, 0, 0);
      c0 = __builtin_amdgcn_mfma_f32_16x16x32_bf16(p3, bv3, c0, 0, 0, 0);
      c1 = __builtin_amdgcn_mfma_f32_16x16x32_bf16(p7, bv3, c1, 0, 0, 0);
      acc0[nt] = c0; acc1[nt] = c1;
    }

    float gg[8], bb[8], ch[8];
    #pragma unroll
    for (int nt = 0; nt < 8; nt++) {
      gg[nt] = g2v[nt*16 + l15]; bb[nt] = b2v[nt*16 + l15]; ch[nt] = 0.f;
    }
    #pragma unroll
    for (int tile = 0; tile < 2; tile++) {
      #pragma unroll
      for (int r = 0; r < 4; r++) {
        float s = 0.f, q = 0.f;
        #pragma unroll
        for (int nt = 0; nt < 8; nt++) {
          float v = tile ? acc1[nt][r] : acc0[nt][r]; s += v; q += v*v;
        }
        #pragma unroll
        for (int mm = 1; mm < 16; mm <<= 1) { s += __shfl_xor(s, mm); q += __shfl_xor(q, mm); }
        float mu = s * (1.f/128.f);
        float var = fmaxf(q * (1.f/128.f) - mu*mu, 0.f);
        float rinv = rsqrtf(var + 1e-5f);
        int orow = wbase + tile*16 + quad*4 + r;
        bool rv = (rowbase + orow) < nrows;
        #pragma unroll
        for (int nt = 0; nt < 8; nt++) {
          float v = ((tile ? acc1[nt][r] : acc0[nt][r]) - mu) * rinv * gg[nt] + bb[nt];
          if (rv) ch[nt] += v;
          xs[orow][nt*16 + l15] = f2bf(v);
        }
      }
    }
    // SE channel partials: reduce across quads, plain store to per-wave bank
    #pragma unroll
    for (int nt = 0; nt < 8; nt++) {
      float v = ch[nt];
      v += __shfl_xor(v, 16); v += __shfl_xor(v, 32);
      if (quad == 0) sqs[wave][nt*16 + l15] = v;
    }
  }

  // per-wave output store: each wave stores its own 32 xs rows (no barrier)
  #pragma unroll
  for (int mm = 0; mm < 8; mm++) {
    int c = mm*64 + (t & 63);       // 512 chunks of 8 shorts = 32 rows x 16
    int rl = wbase + (c >> 4), s8 = c & 15;
    if (rowbase + rl < nrows) {
      short8 v = *(const short8*)&xs[rl][s8*8];
      *(short8*)(Y + (size_t)(rowbase+rl)*128 + s8*8) = v;
    }
  }
  __syncthreads();
  // 32 contention buckets: ~73 blocks per address instead of 2344
  if (t < 128)
    atomicAdd(&sqb[(blockIdx.x & (SQB-1))*128 + t],
              sqs[0][t] + sqs[1][t] + sqs[2][t] + sqs[3][t]);
}

// ---------------- SE: fold buckets -> mean -> fc -> relu -> fc -> sigmoid ----
__global__ void se_kernel(const float* __restrict__ sqb, const float* __restrict__ w1,
    const float* __restrict__ b1, const float* __restrict__ w2,
    const float* __restrict__ b2, float* __restrict__ scale)
{
  __shared__ float mean[128];
  __shared__ float h1[32];
  int t = threadIdx.x; // 128 threads
  float acc = 0.f;
  #pragma unroll
  for (int k = 0; k < SQB; k++) acc += sqb[k*128 + t];
  mean[t] = acc * (1.f/(float)NVOX);
  __syncthreads();
  if(t < 32){
    float s = b1[t];
    for(int c=0;c<128;c++) s += mean[c]*w1[c*32+t];
    h1[t] = fmaxf(s, 0.f);
  }
  __syncthreads();
  float s = b2[t];
  for(int j=0;j<32;j++) s += h1[j]*w2[j*128+t];
  scale[t] = 1.f/(1.f + expf(-s));
}

// ---- scatter: unique rows -> fused relu/valid + PLAIN stores (no atomics);
// duplicated rows (~1e-3 of rows) -> atomicAdd raw sums ----
__global__ void scatter_kernel(const unsigned short* __restrict__ y2,
    const float* __restrict__ feats, const float* __restrict__ scale,
    const int* __restrict__ lin, const unsigned long long* __restrict__ bits,
    const unsigned long long* __restrict__ dupbits,
    const unsigned* __restrict__ coarse, const unsigned* __restrict__ blockExcl,
    float* __restrict__ out_merged, float* __restrict__ out_valid)
{
  int row = blockIdx.x*4 + (threadIdx.x >> 6);
  int lane = threadIdx.x & 63;
  int l = lin[row];
  int w = l >> 6;
  unsigned long long m = 1ull << (l & 63);
  unsigned j = coarse[w] + blockExcl[w >> 12]
             + (unsigned)__popcll(bits[w] & (m - 1ull));
  size_t rb = (size_t)row * 128;
  unsigned yy = *(const unsigned*)(y2 + rb + 2*lane);
  float2 ff = *(const float2*)(feats + rb + 2*lane);
  float2 ss = *(const float2*)(scale + 2*lane);
  float v0 = bf2f((unsigned short)(yy & 0xffffu)) * ss.x + ff.x;
  float v1 = bf2f((unsigned short)(yy >> 16))     * ss.y + ff.y;
  size_t ob = (size_t)j * 128;
  if (dupbits[w] & m) {           // wave-uniform branch (per-row condition)
    atomicAdd(out_merged + ob + 2*lane,     v0);
    atomicAdd(out_merged + ob + 2*lane + 1, v1);
  } else {
    float s = fabsf(v0) + fabsf(v1);
    #pragma unroll
    for(int mm=1; mm<64; mm<<=1) s += __shfl_xor(s, mm);
    bool valid = s > 1e-8f;
    float2 o;
    o.x = valid ? fmaxf(v0, 0.f) : 0.f;
    o.y = valid ? fmaxf(v1, 0.f) : 0.f;
    *(float2*)(out_merged + ob + 2*lane) = o;
    if (lane == 0) out_valid[j] = valid ? 1.f : 0.f;
  }
}

// ------- finalize dup rows (claim via dupbits) + pad rows [U,2N) -----------
// blocks [0,512): dupfinal; [512,1024): pad [U,NVOX) grid-stride;
// [1024, 1024+NVOX/4): pad [NVOX, 2*NVOX) unconditional.
__global__ void dupfinal_pad_kernel(const int* __restrict__ duplist,
    const int* __restrict__ dupcount, const int* __restrict__ lin,
    unsigned long long* __restrict__ dupbits,
    const unsigned long long* __restrict__ bits,
    const unsigned* __restrict__ coarse, const unsigned* __restrict__ blockExcl,
    float* __restrict__ out_merged, float* __restrict__ out_valid,
    float* __restrict__ out_comb)
{
  int lane = threadIdx.x & 63;
  int wv = threadIdx.x >> 6;
  unsigned b = blockIdx.x;
  if (b < 512) {
    int cnt = *dupcount;
    for(int e = b*4 + wv; e < cnt; e += 512*4){
      int l = lin[duplist[e]];
      int w = l >> 6;
      unsigned long long m = 1ull << (l & 63);
      int claimed = 0;
      if (lane == 0){
        unsigned long long old = atomicAnd(&dupbits[w], ~m);
        claimed = (old & m) ? 1 : 0;
      }
      claimed = __shfl(claimed, 0);
      if (!claimed) continue;     // another entry with the same lin owns it
      unsigned j = coarse[w] + blockExcl[w >> 12]
                 + (unsigned)__popcll(bits[w] & (m - 1ull));
      size_t ob = (size_t)j * 128;
      float2 v = *(float2*)(out_merged + ob + 2*lane);
      float s = fabsf(v.x) + fabsf(v.y);
      #pragma unroll
      for(int mm=1; mm<64; mm<<=1) s += __shfl_xor(s, mm);
      bool valid = s > 1e-8f;
      float2 o;
      o.x = valid ? fmaxf(v.x, 0.f) : 0.f;
      o.y = valid ? fmaxf(v.y, 0.f) : 0.f;
      *(float2*)(out_merged + ob + 2*lane) = o;
      if (lane == 0) out_valid[j] = valid ? 1.f : 0.f;
    }
  } else if (b < 1024) {
    unsigned U = blockExcl[128];
    for (unsigned r = U + (b - 512)*4 + wv; r < NVOX; r += 512*4) {
      *(float2*)(out_merged + (size_t)r*128 + 2*lane) = make_float2(0.f, 0.f);
      if (lane == 0) {
        out_valid[r] = 0.f;
        ((float4*)out_comb)[r] = make_float4(8.f, 0.f, 0.f, 0.f);
      }
    }
  } else {
    int r = NVOX + (b - 1024)*4 + wv;
    *(float2*)(out_merged + (size_t)r*128 + 2*lane) = make_float2(0.f, 0.f);
    if (lane == 0) {
      out_valid[r] = 0.f;
      ((float4*)out_comb)[r] = make_float4(8.f, 0.f, 0.f, 0.f);
    }
  }
}

extern "C" void kernel_launch(void* const* d_in, const int* in_sizes, int n_in,
                              void* d_out, int out_size, void* d_ws, size_t ws_size,
                              hipStream_t stream)
{
  const float* feats   = (const float*)d_in[0];
  const int*   indices = (const int*)d_in[1];
  const float* W1  = (const float*)d_in[2];
  const float* g1  = (const float*)d_in[3];
  const float* b1  = (const float*)d_in[4];
  const float* W2  = (const float*)d_in[5];
  const float* g2  = (const float*)d_in[6];
  const float* b2  = (const float*)d_in[7];
  const float* sw1 = (const float*)d_in[8];
  const float* sb1 = (const float*)d_in[9];
  const float* sw2 = (const float*)d_in[10];
  const float* sb2 = (const float*)d_in[11];

  float* out_merged = (float*)d_out;                        // [2N,128]
  float* out_comb   = out_merged + (size_t)2*NVOX*128;      // [2N,4]
  float* out_valid  = out_comb   + (size_t)2*NVOX*4;        // [2N]

  char* cur = (char*)d_ws;
  auto alloc = [&](size_t b) -> void* {
    void* p = (void*)cur;
    cur += (b + 255) & ~(size_t)255;
    return p;
  };
  unsigned short*      y2        = (unsigned short*)alloc((size_t)NVOX*128*2);
  unsigned long long*  bits      = (unsigned long long*)alloc((size_t)NWORDS*8);
  unsigned long long*  dupbits   = (unsigned long long*)alloc((size_t)NWORDS*8); // contiguous w/ bits
  unsigned*            coarse    = (unsigned*)alloc((size_t)NWORDS*4);
  unsigned*            blockSums = (unsigned*)alloc(128*4);
  unsigned*            blockExcl = (unsigned*)alloc(129*4);
  float*               sqb       = (float*)alloc(SQB*128*4);
  int*                 dupcount  = (int*)alloc(4);          // contiguous w/ sqb
  float*               scale     = (float*)alloc(128*4);
  int*                 lin       = (int*)alloc((size_t)NVOX*4);
  int*                 duplist   = (int*)alloc((size_t)NVOX*4);
  unsigned short*      w1t       = (unsigned short*)alloc(128*128*2);
  unsigned short*      w2t       = (unsigned short*)alloc(128*128*2);

  // bits + dupbits are adjacent 256-aligned 4MB blocks -> one 8MB clear
  hipMemsetAsync(bits, 0, (size_t)NWORDS*8*2, stream);
  // sqb (16KB) + dupcount (256B slot) adjacent -> one clear
  hipMemsetAsync(sqb, 0, SQB*128*4 + 256, stream);

  pack_w2<<<128, 256, 0, stream>>>(W1, W2, w1t, w2t);

  mark_kernel<<<(NVOX+255)/256, 256, 0, stream>>>(indices, bits, dupbits, lin,
                                                  duplist, dupcount);
  scan1_kernel<<<128, 256, 0, stream>>>(bits, coarse, blockSums);
  scan2_kernel<<<1, 128, 0, stream>>>(blockSums, blockExcl);
  emit_zerodup_kernel<<<2560, 256, 0, stream>>>(bits, coarse, blockExcl, out_comb,
                                                duplist, dupcount, lin, out_merged);

  fused_mlp<<<(NVOX + MLP_ROWS - 1)/MLP_ROWS, 256, 0, stream>>>(
      feats, w1t, g1, b1, w2t, g2, b2, y2, sqb, NVOX);
  se_kernel<<<1, 128, 0, stream>>>(sqb, sw1, sb1, sw2, sb2, scale);

  scatter_kernel<<<NVOX/4, 256, 0, stream>>>(y2, feats, scale, lin, bits, dupbits,
                                             coarse, blockExcl, out_merged, out_valid);
  dupfinal_pad_kernel<<<1024 + NVOX/4, 256, 0, stream>>>(duplist, dupcount, lin,
      dupbits, bits, coarse, blockExcl, out_merged, out_valid, out_comb);
}